// Round 2
// baseline (264.817 us; speedup 1.0000x reference)
//
#include <hip/hip_runtime.h>
#include <hip/hip_bf16.h>
#include <stdint.h>

// Problem constants
#define BATCH 4
#define SEQ   4096
#define HID   1024
#define NH    16
#define HD    64
#define CS    16
#define NCH   256          // SEQ/CS
#define MROWS 16384        // BATCH*SEQ

typedef __attribute__((ext_vector_type(8))) __bf16 bf16x8;
typedef __attribute__((ext_vector_type(4))) float  f32x4;

__device__ __forceinline__ unsigned short f2bf(float f) {
    union { float f; unsigned u; } x; x.f = f;
    unsigned r = x.u + 0x7FFFu + ((x.u >> 16) & 1u);   // RNE
    return (unsigned short)(r >> 16);
}
__device__ __forceinline__ float bf2f(unsigned short v) {
    union { unsigned u; float f; } x; x.u = ((unsigned)v) << 16;
    return x.f;
}

__device__ __forceinline__ void async_copy16(void* lds, const void* g) {
    __builtin_amdgcn_global_load_lds(
        (const __attribute__((address_space(1))) unsigned int*)g,
        (__attribute__((address_space(3))) unsigned int*)lds,
        16, 0, 0);
}

#define FENCE() asm volatile("" ::: "memory")
#define BARRIER() do { FENCE(); __builtin_amdgcn_s_barrier(); FENCE(); } while (0)
#define LGKM0_SB() do { asm volatile("s_waitcnt lgkmcnt(0)" ::: "memory"); \
                        __builtin_amdgcn_sched_barrier(0); } while (0)
#define VM6() asm volatile("s_waitcnt vmcnt(6)" ::: "memory")

// ---------------------------------------------------------------- convert (all inputs, one kernel)
__global__ __launch_bounds__(256) void convert_all_kernel(
    const float* __restrict__ x, const float* __restrict__ W_in,
    const float* __restrict__ W_out, const float* __restrict__ W_gate,
    unsigned short* __restrict__ xb, unsigned short* __restrict__ Wib,
    unsigned short* __restrict__ Wob, unsigned short* __restrict__ Wgb)
{
    int i = blockIdx.x * 256 + threadIdx.x;
    const float4* src; ushort4* dst; int j;
    if (i < 4194304)      { src = (const float4*)x;      dst = (ushort4*)xb;  j = i; }
    else if (i < 4456448) { src = (const float4*)W_in;   dst = (ushort4*)Wib; j = i - 4194304; }
    else if (i < 4718592) { src = (const float4*)W_out;  dst = (ushort4*)Wob; j = i - 4456448; }
    else if (i < 4726784) { src = (const float4*)W_gate; dst = (ushort4*)Wgb; j = i - 4718592; }
    else return;
    float4 v = src[j];
    ushort4 o;
    o.x = f2bf(v.x); o.y = f2bf(v.y); o.z = f2bf(v.z); o.w = f2bf(v.w);
    dst[j] = o;
}

// ---------------------------------------------------------------- GEMM (C = A @ B^T), bf16 in, fp32 out
// 256x256 tile, BK=64, 8 waves (2Mx4N), double-buffered 128KB LDS.
// 8-phase schedule (2 K-tiles/iter), 3-half-tile prefetch depth:
//   reads: ph0 = A(xh0)+all B (16 ds_read_b128), ph2 = A(xh1) (8)
//   B slots free @ph1, A slots free @ph3 -> stage T+2 at ph1..ph4 into
//   just-freed slots; vmcnt(6) only at ph3/ph7 (3 half-tiles stay in
//   flight; issue->wait distance >= 3 phases). XOR-swizzled LDS via
//   pre-swizzled global source (proven, 0 bank conflicts).
#define GBM 256
#define GBN 256
#define GBK 64

__global__ __launch_bounds__(512, 2) void gemm256_kernel(
    const unsigned short* __restrict__ A,
    const unsigned short* __restrict__ Bm,
    float* __restrict__ C, int M, int N, int K)
{
    __shared__ unsigned short As[2][GBM][GBK];   // 64 KB
    __shared__ unsigned short Bs[2][GBN][GBK];   // 64 KB

    const int t = threadIdx.x;
    const int lane = t & 63, w = t >> 6;
    const int wm = w >> 2, wn = w & 3;           // wave grid 2(M) x 4(N)

    // bijective XCD swizzle (gridDim.x % 8 == 0 here: 256 blocks)
    const int nwg = gridDim.x;
    const int cpx = nwg >> 3;
    const int bid = blockIdx.x;
    const int swz = (bid & 7) * cpx + (bid >> 3);
    const int ntile = N >> 8;                    // N/256
    const size_t bm = (size_t)(swz / ntile) * GBM;
    const size_t bn = (size_t)(swz % ntile) * GBN;

    // ---- staging map: thread t covers rows {srow, srow+64} of a 128-row half
    // physical chunk sp of row r holds logical chunk sp ^ (r&7) (pre-swizzled source)
    const int srow = t >> 3;                     // 0..63
    const int sp   = t & 7;
    const int sgc  = sp ^ (srow & 7);
    const unsigned short* Ag = A  + (bm + srow) * (size_t)K + sgc * 8;
    const unsigned short* Bg = Bm + (bn + srow) * (size_t)K + sgc * 8;

    const int fr = lane & 15, fq = lane >> 4;
    const int frl = fr & 7;

    f32x4 acc[8][4];
#pragma unroll
    for (int x = 0; x < 8; x++)
#pragma unroll
        for (int y = 0; y < 4; y++)
            acc[x][y] = (f32x4){0.f, 0.f, 0.f, 0.f};

    bf16x8 afr[4][2];          // current A x-half fragments (reused for xh0/xh1)
    bf16x8 bfr[4][2];          // all B fragments of current tile (read once @ph0)

    // stage half h of K-tile (k-offset kt) into buffer par.
    // h: 0 = A rows 0-127, 1 = A rows 128-255, 2 = B rows 0-127, 3 = B rows 128-255
    auto stage = [&](int par, int h, int kt) {
        if (h < 2) {
            const unsigned short* g = Ag + (size_t)(h * 128) * K + kt;
            unsigned short* l = &As[par][h * 128 + srow][sp * 8];
            async_copy16(l,            g);
            async_copy16(l + 64 * GBK, g + (size_t)64 * K);
        } else {
            const unsigned short* g = Bg + (size_t)((h - 2) * 128) * K + kt;
            unsigned short* l = &Bs[par][(h - 2) * 128 + srow][sp * 8];
            async_copy16(l,            g);
            async_copy16(l + 64 * GBK, g + (size_t)64 * K);
        }
    };
    auto rdA = [&](int par, int xh) {
#pragma unroll
        for (int x = 0; x < 4; x++)
#pragma unroll
            for (int kk = 0; kk < 2; kk++)
                afr[x][kk] = *(const bf16x8*)&As[par][wm * 128 + xh * 64 + x * 16 + fr]
                                                    [((kk * 4 + fq) ^ frl) * 8];
    };
    auto rdB = [&](int par) {
#pragma unroll
        for (int y = 0; y < 4; y++)
#pragma unroll
            for (int kk = 0; kk < 2; kk++)
                bfr[y][kk] = *(const bf16x8*)&Bs[par][wn * 64 + y * 16 + fr]
                                                    [((kk * 4 + fq) ^ frl) * 8];
    };
    auto mm = [&](int xh, int yh) {
        __builtin_amdgcn_s_setprio(1);
#pragma unroll
        for (int kk = 0; kk < 2; kk++)
#pragma unroll
            for (int x = 0; x < 4; x++)
#pragma unroll
                for (int yy = 0; yy < 2; yy++)
                    acc[xh * 4 + x][yh * 2 + yy] = __builtin_amdgcn_mfma_f32_16x16x32_bf16(
                        afr[x][kk], bfr[yh * 2 + yy][kk], acc[xh * 4 + x][yh * 2 + yy], 0, 0, 0);
        __builtin_amdgcn_s_setprio(0);
    };

    const int NT = K >> 6;                 // 16 K-tiles (even)
    const int kmax = (NT - 1) << 6;
    auto kt = [&](int tile) { int k = tile << 6; return k > kmax ? kmax : k; };

    // ---- prologue: tile0 (all 4 halves) + tile1 (B-h0, B-h1, A-h0) = 7 halves
    stage(0, 2, 0); stage(0, 3, 0); stage(0, 0, 0); stage(0, 1, 0);
    stage(1, 2, kt(1)); stage(1, 3, kt(1)); stage(1, 0, kt(1));
    VM6();                                 // drain tile0's 4 halves; 3 in flight
    BARRIER();

    for (int it = 0; it < (NT >> 1); ++it) {
        const int T = it << 1;             // tile T in buf0, T+1 in buf1
        const int kT1 = kt(T + 1), kT2 = kt(T + 2), kT3 = kt(T + 3);
        // ph0: read A(xh0)+all B of buf0; stage A-h1(T+1)->buf1
        rdA(0, 0); rdB(0);
        stage(1, 1, kT1);
        BARRIER(); LGKM0_SB();
        mm(0, 0);
        BARRIER();
        // ph1: B slots of buf0 now free
        stage(0, 2, kT2);
        BARRIER();
        mm(0, 1);
        BARRIER();
        // ph2: read A(xh1) of buf0
        rdA(0, 1);
        stage(0, 3, kT2);
        BARRIER(); LGKM0_SB();
        mm(1, 0);
        BARRIER();
        // ph3: A slots of buf0 now free; counted wait covers ph4-7 reads of buf1
        stage(0, 0, kT2);
        VM6();
        BARRIER();
        mm(1, 1);
        BARRIER();
        // ph4: read A(xh0)+all B of buf1; last buf0 stage
        rdA(1, 0); rdB(1);
        stage(0, 1, kT2);
        BARRIER(); LGKM0_SB();
        mm(0, 0);
        BARRIER();
        // ph5
        stage(1, 2, kT3);
        BARRIER();
        mm(0, 1);
        BARRIER();
        // ph6
        rdA(1, 1);
        stage(1, 3, kT3);
        BARRIER(); LGKM0_SB();
        mm(1, 0);
        BARRIER();
        // ph7: counted wait covers next iteration's ph0-3 reads of buf0
        stage(1, 0, kT3);
        VM6();
        BARRIER();
        mm(1, 1);
        BARRIER();
    }

    // ---- C write (fp32), same fragment->C mapping as verified kernel
#pragma unroll
    for (int x = 0; x < 8; x++) {
#pragma unroll
        for (int y = 0; y < 4; y++) {
            const size_t r0 = bm + wm * 128 + x * 16 + fq * 4;
            const size_t c  = bn + wn * 64 + y * 16 + fr;
#pragma unroll
            for (int rg = 0; rg < 4; rg++)
                C[(r0 + rg) * (size_t)N + c] = acc[x][y][rg];
        }
    }
    // no LDS-DMA may outlive the block (in-flight tail stages)
    asm volatile("s_waitcnt vmcnt(0)" ::: "memory");
}

// ---------------------------------------------------------------- mid: LN + MFMA gates + scan1 (prefix form)
__global__ __launch_bounds__(256) void mid_kernel(
    const float* __restrict__ xp,
    const float* __restrict__ ln_g, const float* __restrict__ ln_b,
    const unsigned short* __restrict__ Wgb,   // bf16 [32][1024]
    const float* __restrict__ bg, const float* __restrict__ eig_raw,
    unsigned short* __restrict__ xln,         // out: [MROWS][1024] bf16
    float* __restrict__ beta_buf,             // out: [MROWS][16]
    float* __restrict__ cum_out,              // out: [1024][16][16]
    float* __restrict__ c15c,                 // out: [1024][16]
    float* __restrict__ hc15)                 // out: [1024][1024]
{
    __shared__ unsigned short sx[16][1032];   // 33KB, +8 pad
    __shared__ float red[4][2][64][4];        // 8KB partial gate accs
    __shared__ float sg[16][32];
    __shared__ float scum[16][16];
    const int t = threadIdx.x, lane = t & 63, w = t >> 6;
    const int bn = blockIdx.x;
    const size_t m0 = (size_t)(bn >> 8) * SEQ + (size_t)(bn & 255) * 16;

    // ---- LayerNorm (row r = t>>4, 64 elems per thread)
    const int r = t >> 4, u = t & 15;
    {
        const float* row = xp + (m0 + r) * 1024;
        float4 v[16];
        float s = 0.f, s2 = 0.f;
#pragma unroll
        for (int i = 0; i < 16; i++) {
            v[i] = *(const float4*)(row + u * 4 + i * 64);
            s  += v[i].x + v[i].y + v[i].z + v[i].w;
            s2 += v[i].x * v[i].x + v[i].y * v[i].y + v[i].z * v[i].z + v[i].w * v[i].w;
        }
#pragma unroll
        for (int off = 1; off < 16; off <<= 1) {
            s  += __shfl_xor(s, off, 64);
            s2 += __shfl_xor(s2, off, 64);
        }
        const float mu = s * (1.f / 1024.f);
        const float var = s2 * (1.f / 1024.f) - mu * mu;
        const float sc = rsqrtf(var + 1e-5f);
        unsigned short* orow = xln + (m0 + r) * 1024;
#pragma unroll
        for (int i = 0; i < 16; i++) {
            const int k = u * 4 + i * 64;
            float4 g4 = *(const float4*)(ln_g + k);
            float4 b4 = *(const float4*)(ln_b + k);
            ushort4 o;
            o.x = f2bf((v[i].x - mu) * sc * g4.x + b4.x);
            o.y = f2bf((v[i].y - mu) * sc * g4.y + b4.y);
            o.z = f2bf((v[i].z - mu) * sc * g4.z + b4.z);
            o.w = f2bf((v[i].w - mu) * sc * g4.w + b4.w);
            *(ushort4*)&sx[r][k] = o;
            *(ushort4*)(orow + k) = o;
        }
    }
    __syncthreads();

    // ---- gates via MFMA: wave w covers K in [w*256,(w+1)*256)
    const int fr = lane & 15, fq = lane >> 4;
    {
        f32x4 acc0 = (f32x4){0.f,0.f,0.f,0.f}, acc1 = (f32x4){0.f,0.f,0.f,0.f};
        const unsigned short* Wr0 = Wgb + (size_t)fr * 1024;
        const unsigned short* Wr1 = Wgb + (size_t)(16 + fr) * 1024;
#pragma unroll
        for (int ks = 0; ks < 8; ks++) {
            const int k0 = w * 256 + ks * 32 + fq * 8;
            bf16x8 af = *(const bf16x8*)&sx[fr][k0];
            bf16x8 b0 = *(const bf16x8*)(Wr0 + k0);
            bf16x8 b1 = *(const bf16x8*)(Wr1 + k0);
            acc0 = __builtin_amdgcn_mfma_f32_16x16x32_bf16(af, b0, acc0, 0, 0, 0);
            acc1 = __builtin_amdgcn_mfma_f32_16x16x32_bf16(af, b1, acc1, 0, 0, 0);
        }
        *(f32x4*)&red[w][0][lane][0] = acc0;
        *(f32x4*)&red[w][1][lane][0] = acc1;
    }
    __syncthreads();
    if (t < 128) {
        const int y = t >> 6, l = t & 63;
        f32x4 s = *(const f32x4*)&red[0][y][l][0];
#pragma unroll
        for (int ww = 1; ww < 4; ww++) {
            f32x4 p = *(const f32x4*)&red[ww][y][l][0];
            s[0] += p[0]; s[1] += p[1]; s[2] += p[2]; s[3] += p[3];
        }
        const int col = y * 16 + (l & 15);
        const int row0 = (l >> 4) * 4;
        const float bias = bg[col];
#pragma unroll
        for (int rg = 0; rg < 4; rg++)
            sg[row0 + rg][col] = 1.f / (1.f + expf(-(s[rg] + bias)));
    }
    __syncthreads();

    // ---- cumprod of a = tanh(eig)*alpha
    if (t < 16) {
        const float ev = tanhf(eig_raw[t]);
        float c = 1.f;
#pragma unroll
        for (int i = 0; i < 16; i++) { c *= ev * sg[i][t]; scum[i][t] = c; }
    }
    // beta out
    beta_buf[(m0 + r) * 16 + u] = sg[r][16 + u];
    __syncthreads();

    // cum/c15 out
    cum_out[(size_t)bn * 256 + t] = scum[t >> 4][t & 15];
    if (t < 16) c15c[bn * 16 + t] = scum[15][t];

    // ---- hc15 via prefix form: hc15 = cum15 * sum_{j<15} bb[j]/cpad[j] + bb[15]
    {
        const int h = t >> 4, d0 = (t & 15) * 4;
        float s0 = 0.f, s1 = 0.f, s2 = 0.f, s3 = 0.f;
        float b0 = 0.f, b1 = 0.f, b2 = 0.f, b3 = 0.f;
        float cprev = 1.f;
#pragma unroll
        for (int j = 0; j < 16; j++) {
            const float bt = sg[j][16 + h];
            ushort4 xv = *(const ushort4*)&sx[j][h * 64 + d0];
            b0 = bt * bf2f(xv.x); b1 = bt * bf2f(xv.y);
            b2 = bt * bf2f(xv.z); b3 = bt * bf2f(xv.w);
            if (j < 15) {
                const float inv = (fabsf(cprev) > 1e-8f) ? (1.f / cprev) : 0.f;
                s0 += b0 * inv; s1 += b1 * inv; s2 += b2 * inv; s3 += b3 * inv;
                cprev = scum[j][h];
            }
        }
        const float c15 = scum[15][h];
        float4 o = { c15 * s0 + b0, c15 * s1 + b1, c15 * s2 + b2, c15 * s3 + b3 };
        *(float4*)(hc15 + (size_t)bn * 1024 + h * 64 + d0) = o;
    }
}

// ---------------------------------------------------------------- scan phase 2 (sequential carry)
__global__ __launch_bounds__(64) void scan2_kernel(
    const float* __restrict__ c15c,      // [1024][16]
    const float* __restrict__ hc15,      // [1024][1024]
    float* __restrict__ carry_in,        // [1024][1024]
    float* __restrict__ h_final)         // [4][1024]
{
    const int p = blockIdx.x * 64 + threadIdx.x;   // 0..4095
    const int b = p >> 10, hd = p & 1023, h = hd >> 6;
    float carry = 0.f;
#pragma unroll 8
    for (int n = 0; n < NCH; n++) {
        const size_t bn = (size_t)b * NCH + n;
        const float c15 = c15c[bn * 16 + h];
        carry_in[bn * 1024 + hd] = carry;
        carry = c15 * carry + hc15[bn * 1024 + hd];
    }
    h_final[(size_t)b * 1024 + hd] = carry;
}

// ---------------------------------------------------------------- scan phase 3: prefix form, register-resident
// h[i] = cum[i]*(carry + sum_{j<i} bb[j]/cpad[j]) + bb[i]
__global__ __launch_bounds__(256) void scan3_kernel(
    const float* __restrict__ cum_buf,
    const float* __restrict__ beta_buf,
    const unsigned short* __restrict__ xln,
    const float* __restrict__ carry_in,
    unsigned short* __restrict__ hall)          // [MROWS][1024] bf16
{
    __shared__ float scum[16][16];
    __shared__ float sbeta[16][16];
    const int t = threadIdx.x;
    const int bn = blockIdx.x;
    const size_t m0 = (size_t)(bn >> 8) * SEQ + (size_t)(bn & 255) * 16;

    scum[t >> 4][t & 15]  = cum_buf[(size_t)bn * 256 + t];
    sbeta[t >> 4][t & 15] = beta_buf[(m0 + (t >> 4)) * 16 + (t & 15)];
    __syncthreads();

    const int h = t >> 4, dq = t & 15;
    const size_t off = h * 64 + dq * 4;
    float4 s = *(const float4*)(carry_in + (size_t)bn * 1024 + off);
    float cprev = 1.f;
#pragma unroll
    for (int i = 0; i < 16; i++) {
        ushort4 xv = *(const ushort4*)(xln + (m0 + i) * 1024 + off);
        const float bt = sbeta[i][h];
        const float b0 = bt * bf2f(xv.x), b1 = bt * bf2f(xv.y),
                    b2 = bt * bf2f(xv.z), b3 = bt * bf2f(xv.w);
        const float ci = scum[i][h];
        ushort4 o;
        o.x = f2bf(ci * s.x + b0); o.y = f2bf(ci * s.y + b1);
        o.z = f2bf(ci * s.z + b2); o.w = f2bf(ci * s.w + b3);
        *(ushort4*)(hall + (m0 + i) * 1024 + off) = o;
        const float inv = (fabsf(cprev) > 1e-8f) ? (1.f / cprev) : 0.f;
        s.x += b0 * inv; s.y += b1 * inv; s.z += b2 * inv; s.w += b3 * inv;
        cprev = ci;
    }
}

// ---------------------------------------------------------------- launch
extern "C" void kernel_launch(void* const* d_in, const int* in_sizes, int n_in,
                              void* d_out, int out_size, void* d_ws, size_t ws_size,
                              hipStream_t stream)
{
    const float* x       = (const float*)d_in[0];
    const float* W_in    = (const float*)d_in[1];
    const float* ln_g    = (const float*)d_in[2];
    const float* ln_b    = (const float*)d_in[3];
    const float* W_gate  = (const float*)d_in[4];
    const float* b_gate  = (const float*)d_in[5];
    const float* eig_raw = (const float*)d_in[6];
    const float* W_out   = (const float*)d_in[7];
    float* out = (float*)d_out;

    char* ws = (char*)d_ws;
    unsigned short* xb   = (unsigned short*)(ws);                   // 32MB; reused as xln after gemm1
    unsigned short* xln  = (unsigned short*)(ws);
    unsigned short* hall = (unsigned short*)(ws + 33554432);        // 32MB
    unsigned short* Wib  = (unsigned short*)(ws + 67108864);        // 2MB
    unsigned short* Wob  = (unsigned short*)(ws + 69206016);        // 2MB
    unsigned short* Wgb  = (unsigned short*)(ws + 71303168);        // 64KB
    float* beta_buf = (float*)(ws + 71368704);                      // 1MB
    float* cum_buf  = (float*)(ws + 72417280);                      // 1MB
    float* c15c     = (float*)(ws + 73465856);                      // 64KB
    float* hc15     = (float*)(ws + 73531392);                      // 4MB
    float* carry_in = (float*)(ws + 77725696);                      // 4MB  (end ~78.2MB)

    float* xp = out;                       // d_out head doubles as xp scratch
    float* h_final = out + 16777216;

    convert_all_kernel<<<18464, 256, 0, stream>>>(x, W_in, W_out, W_gate, xb, Wib, Wob, Wgb);

    // grid = (M/256)*(N/256) = 64*4 = 256 blocks (1 per CU), 512 threads
    gemm256_kernel<<<256, 512, 0, stream>>>(xb, Wib, xp, MROWS, HID, HID);

    mid_kernel<<<1024, 256, 0, stream>>>(xp, ln_g, ln_b, Wgb, b_gate, eig_raw,
                                         xln, beta_buf, cum_buf, c15c, hc15);

    scan2_kernel<<<64, 64, 0, stream>>>(c15c, hc15, carry_in, h_final);
    scan3_kernel<<<1024, 256, 0, stream>>>(cum_buf, beta_buf, xln, carry_in, hall);

    gemm256_kernel<<<256, 512, 0, stream>>>(hall, Wob, out, MROWS, HID, HID);
}

// Round 3
// 255.291 us; speedup vs baseline: 1.0373x; 1.0373x over previous
//
#include <hip/hip_runtime.h>
#include <hip/hip_bf16.h>
#include <stdint.h>

// Problem constants
#define BATCH 4
#define SEQ   4096
#define HID   1024
#define NH    16
#define HD    64
#define CS    16
#define NCH   256          // SEQ/CS
#define MROWS 16384        // BATCH*SEQ

typedef __attribute__((ext_vector_type(8))) __bf16 bf16x8;
typedef __attribute__((ext_vector_type(4))) float  f32x4;

__device__ __forceinline__ unsigned short f2bf(float f) {
    union { float f; unsigned u; } x; x.f = f;
    unsigned r = x.u + 0x7FFFu + ((x.u >> 16) & 1u);   // RNE
    return (unsigned short)(r >> 16);
}
__device__ __forceinline__ float bf2f(unsigned short v) {
    union { unsigned u; float f; } x; x.u = ((unsigned)v) << 16;
    return x.f;
}

__device__ __forceinline__ void async_copy16(void* lds, const void* g) {
    __builtin_amdgcn_global_load_lds(
        (const __attribute__((address_space(1))) unsigned int*)g,
        (__attribute__((address_space(3))) unsigned int*)lds,
        16, 0, 0);
}

// ---------------------------------------------------------------- convert (all inputs, one kernel)
__global__ __launch_bounds__(256) void convert_all_kernel(
    const float* __restrict__ x, const float* __restrict__ W_in,
    const float* __restrict__ W_out, const float* __restrict__ W_gate,
    unsigned short* __restrict__ xb, unsigned short* __restrict__ Wib,
    unsigned short* __restrict__ Wob, unsigned short* __restrict__ Wgb)
{
    int i = blockIdx.x * 256 + threadIdx.x;
    const float4* src; ushort4* dst; int j;
    if (i < 4194304)      { src = (const float4*)x;      dst = (ushort4*)xb;  j = i; }
    else if (i < 4456448) { src = (const float4*)W_in;   dst = (ushort4*)Wib; j = i - 4194304; }
    else if (i < 4718592) { src = (const float4*)W_out;  dst = (ushort4*)Wob; j = i - 4456448; }
    else if (i < 4726784) { src = (const float4*)W_gate; dst = (ushort4*)Wgb; j = i - 4718592; }
    else return;
    float4 v = src[j];
    ushort4 o;
    o.x = f2bf(v.x); o.y = f2bf(v.y); o.z = f2bf(v.z); o.w = f2bf(v.w);
    dst[j] = o;
}

// ---------------------------------------------------------------- GEMM (C = A @ B^T), bf16 in, fp32 out
// 128x128 tile, BK=64, 4 waves (2x2 of 64x64), XOR-swizzled LDS
// (round-0 proven version: 42.2 us, 814 TF on this problem)
__global__ __launch_bounds__(256, 2) void gemm_bt_kernel(
    const unsigned short* __restrict__ A,
    const unsigned short* __restrict__ Bm,
    float* __restrict__ C, int M, int N, int K)
{
    __shared__ unsigned short As[128 * 64];
    __shared__ unsigned short Bs[128 * 64];
    const int t = threadIdx.x;
    const int lane = t & 63, w = t >> 6;
    const int wm = w >> 1, wn = w & 1;
    const size_t bm = (size_t)blockIdx.x * 128;
    const size_t bn = (size_t)blockIdx.y * 128;

    f32x4 acc[4][4];
#pragma unroll
    for (int x = 0; x < 4; x++)
#pragma unroll
        for (int y = 0; y < 4; y++)
            acc[x][y] = (f32x4){0.f, 0.f, 0.f, 0.f};

    const int srow = lane >> 3;
    const int gc   = (lane & 7) ^ (srow & 7);      // swizzled global chunk
    const int scol = gc * 8;
    const unsigned short* Ag = A + (bm + w * 32 + srow) * (size_t)K + scol;
    const unsigned short* Bg = Bm + (bn + w * 32 + srow) * (size_t)K + scol;
    unsigned short* Al = As + (w * 32 + srow) * 64 + (lane & 7) * 8;
    unsigned short* Bl = Bs + (w * 32 + srow) * 64 + (lane & 7) * 8;

    const int fr = lane & 15, fq = lane >> 4;
    const int rl = fr & 7;

    for (int k0 = 0; k0 < K; k0 += 64) {
#pragma unroll
        for (int r = 0; r < 4; r++) {
            async_copy16(Al + r * 8 * 64, Ag + (size_t)r * 8 * K + k0);
            async_copy16(Bl + r * 8 * 64, Bg + (size_t)r * 8 * K + k0);
        }
        __syncthreads();
#pragma unroll
        for (int kk = 0; kk < 64; kk += 32) {
            const int c = (kk >> 3) + fq;
            const int pc = c ^ rl;
            bf16x8 af[4], bfv[4];
#pragma unroll
            for (int x = 0; x < 4; x++) {
                af[x]  = *(const bf16x8*)(As + (wm * 64 + x * 16 + fr) * 64 + pc * 8);
                bfv[x] = *(const bf16x8*)(Bs + (wn * 64 + x * 16 + fr) * 64 + pc * 8);
            }
#pragma unroll
            for (int x = 0; x < 4; x++)
#pragma unroll
                for (int y = 0; y < 4; y++)
                    acc[x][y] = __builtin_amdgcn_mfma_f32_16x16x32_bf16(af[x], bfv[y], acc[x][y], 0, 0, 0);
        }
        __syncthreads();
    }

#pragma unroll
    for (int x = 0; x < 4; x++) {
#pragma unroll
        for (int y = 0; y < 4; y++) {
            size_t r0 = bm + wm * 64 + x * 16 + fq * 4;
            size_t c  = bn + wn * 64 + y * 16 + fr;
#pragma unroll
            for (int rg = 0; rg < 4; rg++)
                C[(r0 + rg) * (size_t)N + c] = acc[x][y][rg];
        }
    }
}

// ---------------------------------------------------------------- mid: LN + MFMA gates + scan1 (prefix form)
__global__ __launch_bounds__(256) void mid_kernel(
    const float* __restrict__ xp,
    const float* __restrict__ ln_g, const float* __restrict__ ln_b,
    const unsigned short* __restrict__ Wgb,   // bf16 [32][1024]
    const float* __restrict__ bg, const float* __restrict__ eig_raw,
    unsigned short* __restrict__ xln,         // out: [MROWS][1024] bf16
    float* __restrict__ beta_buf,             // out: [MROWS][16]
    float* __restrict__ cum_out,              // out: [1024][16][16]
    float* __restrict__ c15c,                 // out: [1024][16]
    float* __restrict__ hc15)                 // out: [1024][1024]
{
    __shared__ unsigned short sx[16][1032];   // 33KB, +8 pad
    __shared__ float red[4][2][64][4];        // 8KB partial gate accs
    __shared__ float sg[16][32];
    __shared__ float scum[16][16];
    const int t = threadIdx.x, lane = t & 63, w = t >> 6;
    const int bn = blockIdx.x;
    const size_t m0 = (size_t)(bn >> 8) * SEQ + (size_t)(bn & 255) * 16;

    // ---- LayerNorm (row r = t>>4, 64 elems per thread)
    const int r = t >> 4, u = t & 15;
    {
        const float* row = xp + (m0 + r) * 1024;
        float4 v[16];
        float s = 0.f, s2 = 0.f;
#pragma unroll
        for (int i = 0; i < 16; i++) {
            v[i] = *(const float4*)(row + u * 4 + i * 64);
            s  += v[i].x + v[i].y + v[i].z + v[i].w;
            s2 += v[i].x * v[i].x + v[i].y * v[i].y + v[i].z * v[i].z + v[i].w * v[i].w;
        }
#pragma unroll
        for (int off = 1; off < 16; off <<= 1) {
            s  += __shfl_xor(s, off, 64);
            s2 += __shfl_xor(s2, off, 64);
        }
        const float mu = s * (1.f / 1024.f);
        const float var = s2 * (1.f / 1024.f) - mu * mu;
        const float sc = rsqrtf(var + 1e-5f);
        unsigned short* orow = xln + (m0 + r) * 1024;
#pragma unroll
        for (int i = 0; i < 16; i++) {
            const int k = u * 4 + i * 64;
            float4 g4 = *(const float4*)(ln_g + k);
            float4 b4 = *(const float4*)(ln_b + k);
            ushort4 o;
            o.x = f2bf((v[i].x - mu) * sc * g4.x + b4.x);
            o.y = f2bf((v[i].y - mu) * sc * g4.y + b4.y);
            o.z = f2bf((v[i].z - mu) * sc * g4.z + b4.z);
            o.w = f2bf((v[i].w - mu) * sc * g4.w + b4.w);
            *(ushort4*)&sx[r][k] = o;
            *(ushort4*)(orow + k) = o;
        }
    }
    __syncthreads();

    // ---- gates via MFMA: wave w covers K in [w*256,(w+1)*256)
    const int fr = lane & 15, fq = lane >> 4;
    {
        f32x4 acc0 = (f32x4){0.f,0.f,0.f,0.f}, acc1 = (f32x4){0.f,0.f,0.f,0.f};
        const unsigned short* Wr0 = Wgb + (size_t)fr * 1024;
        const unsigned short* Wr1 = Wgb + (size_t)(16 + fr) * 1024;
#pragma unroll
        for (int ks = 0; ks < 8; ks++) {
            const int k0 = w * 256 + ks * 32 + fq * 8;
            bf16x8 af = *(const bf16x8*)&sx[fr][k0];
            bf16x8 b0 = *(const bf16x8*)(Wr0 + k0);
            bf16x8 b1 = *(const bf16x8*)(Wr1 + k0);
            acc0 = __builtin_amdgcn_mfma_f32_16x16x32_bf16(af, b0, acc0, 0, 0, 0);
            acc1 = __builtin_amdgcn_mfma_f32_16x16x32_bf16(af, b1, acc1, 0, 0, 0);
        }
        *(f32x4*)&red[w][0][lane][0] = acc0;
        *(f32x4*)&red[w][1][lane][0] = acc1;
    }
    __syncthreads();
    if (t < 128) {
        const int y = t >> 6, l = t & 63;
        f32x4 s = *(const f32x4*)&red[0][y][l][0];
#pragma unroll
        for (int ww = 1; ww < 4; ww++) {
            f32x4 p = *(const f32x4*)&red[ww][y][l][0];
            s[0] += p[0]; s[1] += p[1]; s[2] += p[2]; s[3] += p[3];
        }
        const int col = y * 16 + (l & 15);
        const int row0 = (l >> 4) * 4;
        const float bias = bg[col];
#pragma unroll
        for (int rg = 0; rg < 4; rg++)
            sg[row0 + rg][col] = 1.f / (1.f + expf(-(s[rg] + bias)));
    }
    __syncthreads();

    // ---- cumprod of a = tanh(eig)*alpha
    if (t < 16) {
        const float ev = tanhf(eig_raw[t]);
        float c = 1.f;
#pragma unroll
        for (int i = 0; i < 16; i++) { c *= ev * sg[i][t]; scum[i][t] = c; }
    }
    // beta out
    beta_buf[(m0 + r) * 16 + u] = sg[r][16 + u];
    __syncthreads();

    // cum/c15 out
    cum_out[(size_t)bn * 256 + t] = scum[t >> 4][t & 15];
    if (t < 16) c15c[bn * 16 + t] = scum[15][t];

    // ---- hc15 via prefix form: hc15 = cum15 * sum_{j<15} bb[j]/cpad[j] + bb[15]
    {
        const int h = t >> 4, d0 = (t & 15) * 4;
        float s0 = 0.f, s1 = 0.f, s2 = 0.f, s3 = 0.f;
        float b0 = 0.f, b1 = 0.f, b2 = 0.f, b3 = 0.f;
        float cprev = 1.f;
#pragma unroll
        for (int j = 0; j < 16; j++) {
            const float bt = sg[j][16 + h];
            ushort4 xv = *(const ushort4*)&sx[j][h * 64 + d0];
            b0 = bt * bf2f(xv.x); b1 = bt * bf2f(xv.y);
            b2 = bt * bf2f(xv.z); b3 = bt * bf2f(xv.w);
            if (j < 15) {
                const float inv = (fabsf(cprev) > 1e-8f) ? (1.f / cprev) : 0.f;
                s0 += b0 * inv; s1 += b1 * inv; s2 += b2 * inv; s3 += b3 * inv;
                cprev = scum[j][h];
            }
        }
        const float c15 = scum[15][h];
        float4 o = { c15 * s0 + b0, c15 * s1 + b1, c15 * s2 + b2, c15 * s3 + b3 };
        *(float4*)(hc15 + (size_t)bn * 1024 + h * 64 + d0) = o;
    }
}

// ---------------------------------------------------------------- hierarchical inter-chunk scan
// Carry recursion carry' = c15*carry + hc15 is an affine-map composition:
// level A composes 16-chunk groups into (P,S); level B scans the 16 groups;
// level C reconstructs per-chunk carry_in. Serial depth 256 -> 3x16 steps,
// at 65536 / 4096 / 65536 threads (vs old scan2's 4096 threads, 256 steps).
__global__ __launch_bounds__(256) void scan2a_kernel(
    const float* __restrict__ c15c,      // [1024][16]
    const float* __restrict__ hc15,      // [1024][1024]
    float* __restrict__ Pg,              // [4][16][1024]
    float* __restrict__ Sg)              // [4][16][1024]
{
    const int tid = blockIdx.x * 256 + threadIdx.x;      // 0..65535
    const int b = tid >> 14, g = (tid >> 10) & 15, hd = tid & 1023, h = hd >> 6;
    const int n0 = b * NCH + g * 16;
    float P = 1.f, S = 0.f;
#pragma unroll
    for (int j = 0; j < 16; j++) {
        const float c = c15c[(n0 + j) * 16 + h];
        S = c * S + hc15[(size_t)(n0 + j) * 1024 + hd];
        P = c * P;
    }
    Pg[tid] = P;
    Sg[tid] = S;
}

__global__ __launch_bounds__(64) void scan2b_kernel(
    const float* __restrict__ Pg, const float* __restrict__ Sg,
    float* __restrict__ GC,              // [4][16][1024] group carry-in
    float* __restrict__ h_final)         // [4][1024]
{
    const int p = blockIdx.x * 64 + threadIdx.x;         // 0..4095 = (b,hd)
    const int b = p >> 10, hd = p & 1023;
    float gc = 0.f;
#pragma unroll
    for (int g = 0; g < 16; g++) {
        const int idx = (b * 16 + g) * 1024 + hd;
        GC[idx] = gc;
        gc = Pg[idx] * gc + Sg[idx];
    }
    h_final[p] = gc;
}

__global__ __launch_bounds__(256) void scan2c_kernel(
    const float* __restrict__ c15c, const float* __restrict__ hc15,
    const float* __restrict__ GC,
    float* __restrict__ carry_in)        // [1024][1024]
{
    const int tid = blockIdx.x * 256 + threadIdx.x;      // 0..65535
    const int b = tid >> 14, g = (tid >> 10) & 15, hd = tid & 1023, h = hd >> 6;
    const int n0 = b * NCH + g * 16;
    float s = GC[tid];
#pragma unroll
    for (int j = 0; j < 16; j++) {
        const size_t bn = n0 + j;
        carry_in[bn * 1024 + hd] = s;
        s = c15c[bn * 16 + h] * s + hc15[bn * 1024 + hd];
    }
}

// ---------------------------------------------------------------- scan phase 3: prefix form, register-resident
// h[i] = cum[i]*(carry + sum_{j<i} bb[j]/cpad[j]) + bb[i]
__global__ __launch_bounds__(256) void scan3_kernel(
    const float* __restrict__ cum_buf,
    const float* __restrict__ beta_buf,
    const unsigned short* __restrict__ xln,
    const float* __restrict__ carry_in,
    unsigned short* __restrict__ hall)          // [MROWS][1024] bf16
{
    __shared__ float scum[16][16];
    __shared__ float sbeta[16][16];
    const int t = threadIdx.x;
    const int bn = blockIdx.x;
    const size_t m0 = (size_t)(bn >> 8) * SEQ + (size_t)(bn & 255) * 16;

    scum[t >> 4][t & 15]  = cum_buf[(size_t)bn * 256 + t];
    sbeta[t >> 4][t & 15] = beta_buf[(m0 + (t >> 4)) * 16 + (t & 15)];
    __syncthreads();

    const int h = t >> 4, dq = t & 15;
    const size_t off = h * 64 + dq * 4;
    float4 s = *(const float4*)(carry_in + (size_t)bn * 1024 + off);
    float cprev = 1.f;
#pragma unroll
    for (int i = 0; i < 16; i++) {
        ushort4 xv = *(const ushort4*)(xln + (m0 + i) * 1024 + off);
        const float bt = sbeta[i][h];
        const float b0 = bt * bf2f(xv.x), b1 = bt * bf2f(xv.y),
                    b2 = bt * bf2f(xv.z), b3 = bt * bf2f(xv.w);
        const float ci = scum[i][h];
        ushort4 o;
        o.x = f2bf(ci * s.x + b0); o.y = f2bf(ci * s.y + b1);
        o.z = f2bf(ci * s.z + b2); o.w = f2bf(ci * s.w + b3);
        *(ushort4*)(hall + (m0 + i) * 1024 + off) = o;
        const float inv = (fabsf(cprev) > 1e-8f) ? (1.f / cprev) : 0.f;
        s.x += b0 * inv; s.y += b1 * inv; s.z += b2 * inv; s.w += b3 * inv;
        cprev = ci;
    }
}

// ---------------------------------------------------------------- launch
extern "C" void kernel_launch(void* const* d_in, const int* in_sizes, int n_in,
                              void* d_out, int out_size, void* d_ws, size_t ws_size,
                              hipStream_t stream)
{
    const float* x       = (const float*)d_in[0];
    const float* W_in    = (const float*)d_in[1];
    const float* ln_g    = (const float*)d_in[2];
    const float* ln_b    = (const float*)d_in[3];
    const float* W_gate  = (const float*)d_in[4];
    const float* b_gate  = (const float*)d_in[5];
    const float* eig_raw = (const float*)d_in[6];
    const float* W_out   = (const float*)d_in[7];
    float* out = (float*)d_out;

    char* ws = (char*)d_ws;
    unsigned short* xb   = (unsigned short*)(ws);                   // 32MB; reused as xln after gemm1
    unsigned short* xln  = (unsigned short*)(ws);
    unsigned short* hall = (unsigned short*)(ws + 33554432);        // 32MB
    unsigned short* Wib  = (unsigned short*)(ws + 67108864);        // 2MB
    unsigned short* Wob  = (unsigned short*)(ws + 69206016);        // 2MB
    unsigned short* Wgb  = (unsigned short*)(ws + 71303168);        // 64KB
    float* beta_buf = (float*)(ws + 71368704);                      // 1MB
    float* cum_buf  = (float*)(ws + 72417280);                      // 1MB
    float* c15c     = (float*)(ws + 73465856);                      // 64KB
    float* hc15     = (float*)(ws + 73531392);                      // 4MB
    float* carry_in = (float*)(ws + 77725696);                      // 4MB  (end ~78.2MB)

    // scan scratch lives in the hall region (dead until scan3 writes it)
    float* Pg = (float*)(ws + 33554432);                            // 256KB
    float* Sg = (float*)(ws + 33554432 + 262144);                   // 256KB
    float* GC = (float*)(ws + 33554432 + 524288);                   // 256KB

    float* xp = out;                       // d_out head doubles as xp scratch
    float* h_final = out + 16777216;

    convert_all_kernel<<<18464, 256, 0, stream>>>(x, W_in, W_out, W_gate, xb, Wib, Wob, Wgb);

    dim3 gg(128, 8);
    gemm_bt_kernel<<<gg, 256, 0, stream>>>(xb, Wib, xp, MROWS, HID, HID);

    mid_kernel<<<1024, 256, 0, stream>>>(xp, ln_g, ln_b, Wgb, b_gate, eig_raw,
                                         xln, beta_buf, cum_buf, c15c, hc15);

    scan2a_kernel<<<256, 256, 0, stream>>>(c15c, hc15, Pg, Sg);
    scan2b_kernel<<<64, 64, 0, stream>>>(Pg, Sg, GC, h_final);
    scan2c_kernel<<<256, 256, 0, stream>>>(c15c, hc15, GC, carry_in);

    scan3_kernel<<<1024, 256, 0, stream>>>(cum_buf, beta_buf, xln, carry_in, hall);

    gemm_bt_kernel<<<gg, 256, 0, stream>>>(hall, Wob, out, MROWS, HID, HID);
}

// Round 4
// 253.503 us; speedup vs baseline: 1.0446x; 1.0071x over previous
//
#include <hip/hip_runtime.h>
#include <hip/hip_bf16.h>
#include <stdint.h>

// Problem constants
#define BATCH 4
#define SEQ   4096
#define HID   1024
#define NH    16
#define HD    64
#define CS    16
#define NCH   256          // SEQ/CS
#define MROWS 16384        // BATCH*SEQ

typedef __attribute__((ext_vector_type(8))) __bf16 bf16x8;
typedef __attribute__((ext_vector_type(4))) float  f32x4;
typedef __attribute__((ext_vector_type(8))) unsigned short u16x8;

__device__ __forceinline__ unsigned short f2bf(float f) {
    union { float f; unsigned u; } x; x.f = f;
    unsigned r = x.u + 0x7FFFu + ((x.u >> 16) & 1u);   // RNE
    return (unsigned short)(r >> 16);
}
__device__ __forceinline__ float bf2f(unsigned short v) {
    union { unsigned u; float f; } x; x.u = ((unsigned)v) << 16;
    return x.f;
}

__device__ __forceinline__ void async_copy16(void* lds, const void* g) {
    __builtin_amdgcn_global_load_lds(
        (const __attribute__((address_space(1))) unsigned int*)g,
        (__attribute__((address_space(3))) unsigned int*)lds,
        16, 0, 0);
}

// ---------------------------------------------------------------- convert (all inputs, one kernel)
// 8 floats/thread: 2x float4 loads, 1x 16B ushort8 store
__global__ __launch_bounds__(256) void convert_all_kernel(
    const float* __restrict__ x, const float* __restrict__ W_in,
    const float* __restrict__ W_out, const float* __restrict__ W_gate,
    unsigned short* __restrict__ xb, unsigned short* __restrict__ Wib,
    unsigned short* __restrict__ Wob, unsigned short* __restrict__ Wgb)
{
    int i = blockIdx.x * 256 + threadIdx.x;        // unit = 8 floats
    const float4* src; u16x8* dst; int j;
    if (i < 2097152)      { src = (const float4*)x;      dst = (u16x8*)xb;  j = i; }
    else if (i < 2228224) { src = (const float4*)W_in;   dst = (u16x8*)Wib; j = i - 2097152; }
    else if (i < 2359296) { src = (const float4*)W_out;  dst = (u16x8*)Wob; j = i - 2228224; }
    else if (i < 2363392) { src = (const float4*)W_gate; dst = (u16x8*)Wgb; j = i - 2359296; }
    else return;
    float4 a = src[2 * j], b = src[2 * j + 1];
    u16x8 o;
    o[0] = f2bf(a.x); o[1] = f2bf(a.y); o[2] = f2bf(a.z); o[3] = f2bf(a.w);
    o[4] = f2bf(b.x); o[5] = f2bf(b.y); o[6] = f2bf(b.z); o[7] = f2bf(b.w);
    dst[j] = o;
}

// ---------------------------------------------------------------- GEMM (C = A @ B^T), bf16 in, fp32 out
// 128x128 tile, BK=64, 4 waves (2x2 of 64x64), XOR-swizzled LDS
// (round-0 proven version: 42.2 us, 814 TF on this problem — do not touch)
__global__ __launch_bounds__(256, 2) void gemm_bt_kernel(
    const unsigned short* __restrict__ A,
    const unsigned short* __restrict__ Bm,
    float* __restrict__ C, int M, int N, int K)
{
    __shared__ unsigned short As[128 * 64];
    __shared__ unsigned short Bs[128 * 64];
    const int t = threadIdx.x;
    const int lane = t & 63, w = t >> 6;
    const int wm = w >> 1, wn = w & 1;
    const size_t bm = (size_t)blockIdx.x * 128;
    const size_t bn = (size_t)blockIdx.y * 128;

    f32x4 acc[4][4];
#pragma unroll
    for (int x = 0; x < 4; x++)
#pragma unroll
        for (int y = 0; y < 4; y++)
            acc[x][y] = (f32x4){0.f, 0.f, 0.f, 0.f};

    const int srow = lane >> 3;
    const int gc   = (lane & 7) ^ (srow & 7);      // swizzled global chunk
    const int scol = gc * 8;
    const unsigned short* Ag = A + (bm + w * 32 + srow) * (size_t)K + scol;
    const unsigned short* Bg = Bm + (bn + w * 32 + srow) * (size_t)K + scol;
    unsigned short* Al = As + (w * 32 + srow) * 64 + (lane & 7) * 8;
    unsigned short* Bl = Bs + (w * 32 + srow) * 64 + (lane & 7) * 8;

    const int fr = lane & 15, fq = lane >> 4;
    const int rl = fr & 7;

    for (int k0 = 0; k0 < K; k0 += 64) {
#pragma unroll
        for (int r = 0; r < 4; r++) {
            async_copy16(Al + r * 8 * 64, Ag + (size_t)r * 8 * K + k0);
            async_copy16(Bl + r * 8 * 64, Bg + (size_t)r * 8 * K + k0);
        }
        __syncthreads();
#pragma unroll
        for (int kk = 0; kk < 64; kk += 32) {
            const int c = (kk >> 3) + fq;
            const int pc = c ^ rl;
            bf16x8 af[4], bfv[4];
#pragma unroll
            for (int x = 0; x < 4; x++) {
                af[x]  = *(const bf16x8*)(As + (wm * 64 + x * 16 + fr) * 64 + pc * 8);
                bfv[x] = *(const bf16x8*)(Bs + (wn * 64 + x * 16 + fr) * 64 + pc * 8);
            }
#pragma unroll
            for (int x = 0; x < 4; x++)
#pragma unroll
                for (int y = 0; y < 4; y++)
                    acc[x][y] = __builtin_amdgcn_mfma_f32_16x16x32_bf16(af[x], bfv[y], acc[x][y], 0, 0, 0);
        }
        __syncthreads();
    }

#pragma unroll
    for (int x = 0; x < 4; x++) {
#pragma unroll
        for (int y = 0; y < 4; y++) {
            size_t r0 = bm + wm * 64 + x * 16 + fq * 4;
            size_t c  = bn + wn * 64 + y * 16 + fr;
#pragma unroll
            for (int rg = 0; rg < 4; rg++)
                C[(r0 + rg) * (size_t)N + c] = acc[x][y][rg];
        }
    }
}

// ---------------------------------------------------------------- mid: LN + MFMA gates + scan1 (prefix form)
__global__ __launch_bounds__(256) void mid_kernel(
    const float* __restrict__ xp,
    const float* __restrict__ ln_g, const float* __restrict__ ln_b,
    const unsigned short* __restrict__ Wgb,   // bf16 [32][1024]
    const float* __restrict__ bg, const float* __restrict__ eig_raw,
    unsigned short* __restrict__ xln,         // out: [MROWS][1024] bf16
    float* __restrict__ beta_buf,             // out: [MROWS][16]
    float* __restrict__ cum_out,              // out: [1024][16][16]
    float* __restrict__ c15c,                 // out: [1024][16]
    float* __restrict__ hc15)                 // out: [1024][1024]
{
    __shared__ unsigned short sx[16][1032];   // 33KB, +8 pad
    __shared__ float red[4][2][64][4];        // 8KB partial gate accs
    __shared__ float sg[16][32];
    __shared__ float scum[16][16];
    const int t = threadIdx.x, lane = t & 63, w = t >> 6;
    const int bn = blockIdx.x;
    const size_t m0 = (size_t)(bn >> 8) * SEQ + (size_t)(bn & 255) * 16;

    // ---- LayerNorm (row r = t>>4, 64 elems per thread, 8-consecutive slices)
    const int r = t >> 4, u = t & 15;
    {
        const float* row = xp + (m0 + r) * 1024;
        float4 va[8], vb[8];
        float s = 0.f, s2 = 0.f;
#pragma unroll
        for (int i = 0; i < 8; i++) {
            const int k = u * 8 + i * 128;
            va[i] = *(const float4*)(row + k);
            vb[i] = *(const float4*)(row + k + 4);
            s  += va[i].x + va[i].y + va[i].z + va[i].w
                + vb[i].x + vb[i].y + vb[i].z + vb[i].w;
            s2 += va[i].x * va[i].x + va[i].y * va[i].y + va[i].z * va[i].z + va[i].w * va[i].w
                + vb[i].x * vb[i].x + vb[i].y * vb[i].y + vb[i].z * vb[i].z + vb[i].w * vb[i].w;
        }
#pragma unroll
        for (int off = 1; off < 16; off <<= 1) {
            s  += __shfl_xor(s, off, 64);
            s2 += __shfl_xor(s2, off, 64);
        }
        const float mu = s * (1.f / 1024.f);
        const float var = s2 * (1.f / 1024.f) - mu * mu;
        const float sc = rsqrtf(var + 1e-5f);
        unsigned short* orow = xln + (m0 + r) * 1024;
#pragma unroll
        for (int i = 0; i < 8; i++) {
            const int k = u * 8 + i * 128;
            float4 g4a = *(const float4*)(ln_g + k);
            float4 g4b = *(const float4*)(ln_g + k + 4);
            float4 b4a = *(const float4*)(ln_b + k);
            float4 b4b = *(const float4*)(ln_b + k + 4);
            u16x8 o;
            o[0] = f2bf((va[i].x - mu) * sc * g4a.x + b4a.x);
            o[1] = f2bf((va[i].y - mu) * sc * g4a.y + b4a.y);
            o[2] = f2bf((va[i].z - mu) * sc * g4a.z + b4a.z);
            o[3] = f2bf((va[i].w - mu) * sc * g4a.w + b4a.w);
            o[4] = f2bf((vb[i].x - mu) * sc * g4b.x + b4b.x);
            o[5] = f2bf((vb[i].y - mu) * sc * g4b.y + b4b.y);
            o[6] = f2bf((vb[i].z - mu) * sc * g4b.z + b4b.z);
            o[7] = f2bf((vb[i].w - mu) * sc * g4b.w + b4b.w);
            *(u16x8*)&sx[r][k] = o;
            *(u16x8*)(orow + k) = o;
        }
    }
    __syncthreads();

    // ---- gates via MFMA: wave w covers K in [w*256,(w+1)*256)
    const int fr = lane & 15, fq = lane >> 4;
    {
        f32x4 acc0 = (f32x4){0.f,0.f,0.f,0.f}, acc1 = (f32x4){0.f,0.f,0.f,0.f};
        const unsigned short* Wr0 = Wgb + (size_t)fr * 1024;
        const unsigned short* Wr1 = Wgb + (size_t)(16 + fr) * 1024;
#pragma unroll
        for (int ks = 0; ks < 8; ks++) {
            const int k0 = w * 256 + ks * 32 + fq * 8;
            bf16x8 af = *(const bf16x8*)&sx[fr][k0];
            bf16x8 b0 = *(const bf16x8*)(Wr0 + k0);
            bf16x8 b1 = *(const bf16x8*)(Wr1 + k0);
            acc0 = __builtin_amdgcn_mfma_f32_16x16x32_bf16(af, b0, acc0, 0, 0, 0);
            acc1 = __builtin_amdgcn_mfma_f32_16x16x32_bf16(af, b1, acc1, 0, 0, 0);
        }
        *(f32x4*)&red[w][0][lane][0] = acc0;
        *(f32x4*)&red[w][1][lane][0] = acc1;
    }
    __syncthreads();
    if (t < 128) {
        const int y = t >> 6, l = t & 63;
        f32x4 s = *(const f32x4*)&red[0][y][l][0];
#pragma unroll
        for (int ww = 1; ww < 4; ww++) {
            f32x4 p = *(const f32x4*)&red[ww][y][l][0];
            s[0] += p[0]; s[1] += p[1]; s[2] += p[2]; s[3] += p[3];
        }
        const int col = y * 16 + (l & 15);
        const int row0 = (l >> 4) * 4;
        const float bias = bg[col];
#pragma unroll
        for (int rg = 0; rg < 4; rg++)
            sg[row0 + rg][col] = 1.f / (1.f + expf(-(s[rg] + bias)));
    }
    __syncthreads();

    // ---- cumprod of a = tanh(eig)*alpha
    if (t < 16) {
        const float ev = tanhf(eig_raw[t]);
        float c = 1.f;
#pragma unroll
        for (int i = 0; i < 16; i++) { c *= ev * sg[i][t]; scum[i][t] = c; }
    }
    // beta out
    beta_buf[(m0 + r) * 16 + u] = sg[r][16 + u];
    __syncthreads();

    // cum/c15 out
    cum_out[(size_t)bn * 256 + t] = scum[t >> 4][t & 15];
    if (t < 16) c15c[bn * 16 + t] = scum[15][t];

    // ---- hc15 via prefix form: hc15 = cum15 * sum_{j<15} bb[j]/cpad[j] + bb[15]
    {
        const int h = t >> 4, d0 = (t & 15) * 4;
        float s0 = 0.f, s1 = 0.f, s2 = 0.f, s3 = 0.f;
        float b0 = 0.f, b1 = 0.f, b2 = 0.f, b3 = 0.f;
        float cprev = 1.f;
#pragma unroll
        for (int j = 0; j < 16; j++) {
            const float bt = sg[j][16 + h];
            ushort4 xv = *(const ushort4*)&sx[j][h * 64 + d0];
            b0 = bt * bf2f(xv.x); b1 = bt * bf2f(xv.y);
            b2 = bt * bf2f(xv.z); b3 = bt * bf2f(xv.w);
            if (j < 15) {
                const float inv = (fabsf(cprev) > 1e-8f) ? (1.f / cprev) : 0.f;
                s0 += b0 * inv; s1 += b1 * inv; s2 += b2 * inv; s3 += b3 * inv;
                cprev = scum[j][h];
            }
        }
        const float c15 = scum[15][h];
        float4 o = { c15 * s0 + b0, c15 * s1 + b1, c15 * s2 + b2, c15 * s3 + b3 };
        *(float4*)(hc15 + (size_t)bn * 1024 + h * 64 + d0) = o;
    }
}

// ---------------------------------------------------------------- hierarchical inter-chunk scan
// Level A: compose 16-chunk groups into affine (P,S).
__global__ __launch_bounds__(256) void scan2a_kernel(
    const float* __restrict__ c15c,      // [1024][16]
    const float* __restrict__ hc15,      // [1024][1024]
    float* __restrict__ Pg,              // [4][16][1024]
    float* __restrict__ Sg)              // [4][16][1024]
{
    const int tid = blockIdx.x * 256 + threadIdx.x;      // 0..65535
    const int b = tid >> 14, g = (tid >> 10) & 15, hd = tid & 1023, h = hd >> 6;
    const int n0 = b * NCH + g * 16;
    float P = 1.f, S = 0.f;
#pragma unroll
    for (int j = 0; j < 16; j++) {
        const float c = c15c[(n0 + j) * 16 + h];
        S = c * S + hc15[(size_t)(n0 + j) * 1024 + hd];
        P = c * P;
    }
    Pg[tid] = P;
    Sg[tid] = S;
}

// Level B+C merged: each thread redoes its group-prefix (<=15 L2-resident
// fmadd steps, wave-uniform loop) then reconstructs per-chunk carry_in;
// the g==15 thread's final carry is h_final.
__global__ __launch_bounds__(256) void scan2c_kernel(
    const float* __restrict__ c15c, const float* __restrict__ hc15,
    const float* __restrict__ Pg, const float* __restrict__ Sg,
    float* __restrict__ carry_in,        // [1024][1024]
    float* __restrict__ h_final)         // [4][1024]
{
    const int tid = blockIdx.x * 256 + threadIdx.x;      // 0..65535
    const int b = tid >> 14, g = (tid >> 10) & 15, hd = tid & 1023, h = hd >> 6;
    const int n0 = b * NCH + g * 16;
    float s = 0.f;
    for (int gp = 0; gp < g; gp++) {                     // wave-uniform trip count
        const int idx = ((b * 16 + gp) << 10) + hd;
        s = Pg[idx] * s + Sg[idx];
    }
#pragma unroll
    for (int j = 0; j < 16; j++) {
        const size_t bn = n0 + j;
        carry_in[bn * 1024 + hd] = s;
        s = c15c[bn * 16 + h] * s + hc15[bn * 1024 + hd];
    }
    if (g == 15) h_final[(b << 10) + hd] = s;
}

// ---------------------------------------------------------------- scan phase 3: prefix form, register-resident
// h[i] = cum[i]*(carry + sum_{j<i} bb[j]/cpad[j]) + bb[i]
// 128 threads/block, 8-elem column slices: 16B loads/stores throughout.
__global__ __launch_bounds__(128) void scan3_kernel(
    const float* __restrict__ cum_buf,
    const float* __restrict__ beta_buf,
    const unsigned short* __restrict__ xln,
    const float* __restrict__ carry_in,
    unsigned short* __restrict__ hall)          // [MROWS][1024] bf16
{
    __shared__ float scum[16][16];
    __shared__ float sbeta[16][16];
    const int t = threadIdx.x;                  // 0..127
    const int bn = blockIdx.x;
    const size_t m0 = (size_t)(bn >> 8) * SEQ + (size_t)(bn & 255) * 16;

    {
        const int i0 = t, i1 = t + 128;
        scum[i0 >> 4][i0 & 15]  = cum_buf[(size_t)bn * 256 + i0];
        scum[i1 >> 4][i1 & 15]  = cum_buf[(size_t)bn * 256 + i1];
        sbeta[i0 >> 4][i0 & 15] = beta_buf[(m0 + (i0 >> 4)) * 16 + (i0 & 15)];
        sbeta[i1 >> 4][i1 & 15] = beta_buf[(m0 + (i1 >> 4)) * 16 + (i1 & 15)];
    }
    __syncthreads();

    const int h = t >> 3, dq = t & 7;
    const size_t off = h * 64 + dq * 8;
    float s[8];
    *(float4*)&s[0] = *(const float4*)(carry_in + (size_t)bn * 1024 + off);
    *(float4*)&s[4] = *(const float4*)(carry_in + (size_t)bn * 1024 + off + 4);
    float cprev = 1.f;
#pragma unroll
    for (int i = 0; i < 16; i++) {
        u16x8 xv = *(const u16x8*)(xln + (m0 + i) * 1024 + off);
        const float bt = sbeta[i][h];
        const float ci = scum[i][h];
        float bb[8];
        u16x8 o;
#pragma unroll
        for (int e = 0; e < 8; e++) {
            bb[e] = bt * bf2f(xv[e]);
            o[e] = f2bf(ci * s[e] + bb[e]);
        }
        *(u16x8*)(hall + (m0 + i) * 1024 + off) = o;
        const float inv = (fabsf(cprev) > 1e-8f) ? (1.f / cprev) : 0.f;
#pragma unroll
        for (int e = 0; e < 8; e++)
            s[e] += bb[e] * inv;
        cprev = ci;
    }
}

// ---------------------------------------------------------------- launch
extern "C" void kernel_launch(void* const* d_in, const int* in_sizes, int n_in,
                              void* d_out, int out_size, void* d_ws, size_t ws_size,
                              hipStream_t stream)
{
    const float* x       = (const float*)d_in[0];
    const float* W_in    = (const float*)d_in[1];
    const float* ln_g    = (const float*)d_in[2];
    const float* ln_b    = (const float*)d_in[3];
    const float* W_gate  = (const float*)d_in[4];
    const float* b_gate  = (const float*)d_in[5];
    const float* eig_raw = (const float*)d_in[6];
    const float* W_out   = (const float*)d_in[7];
    float* out = (float*)d_out;

    char* ws = (char*)d_ws;
    unsigned short* xb   = (unsigned short*)(ws);                   // 32MB; reused as xln after gemm1
    unsigned short* xln  = (unsigned short*)(ws);
    unsigned short* hall = (unsigned short*)(ws + 33554432);        // 32MB
    unsigned short* Wib  = (unsigned short*)(ws + 67108864);        // 2MB
    unsigned short* Wob  = (unsigned short*)(ws + 69206016);        // 2MB
    unsigned short* Wgb  = (unsigned short*)(ws + 71303168);        // 64KB
    float* beta_buf = (float*)(ws + 71368704);                      // 1MB
    float* cum_buf  = (float*)(ws + 72417280);                      // 1MB
    float* c15c     = (float*)(ws + 73465856);                      // 64KB
    float* hc15     = (float*)(ws + 73531392);                      // 4MB
    float* carry_in = (float*)(ws + 77725696);                      // 4MB  (end ~78.2MB)

    // scan scratch lives in the hall region (dead until scan3 writes it)
    float* Pg = (float*)(ws + 33554432);                            // 256KB
    float* Sg = (float*)(ws + 33554432 + 262144);                   // 256KB

    float* xp = out;                       // d_out head doubles as xp scratch
    float* h_final = out + 16777216;

    convert_all_kernel<<<9232, 256, 0, stream>>>(x, W_in, W_out, W_gate, xb, Wib, Wob, Wgb);

    dim3 gg(128, 8);
    gemm_bt_kernel<<<gg, 256, 0, stream>>>(xb, Wib, xp, MROWS, HID, HID);

    mid_kernel<<<1024, 256, 0, stream>>>(xp, ln_g, ln_b, Wgb, b_gate, eig_raw,
                                         xln, beta_buf, cum_buf, c15c, hc15);

    scan2a_kernel<<<256, 256, 0, stream>>>(c15c, hc15, Pg, Sg);
    scan2c_kernel<<<256, 256, 0, stream>>>(c15c, hc15, Pg, Sg, carry_in, h_final);

    scan3_kernel<<<1024, 128, 0, stream>>>(cum_buf, beta_buf, xln, carry_in, hall);

    gemm_bt_kernel<<<gg, 256, 0, stream>>>(hall, Wob, out, MROWS, HID, HID);
}